// Round 4
// baseline (177.744 us; speedup 1.0000x reference)
//
#include <hip/hip_runtime.h>

#define EPS 1e-5f

// ===========================================================================
// ws layout (float offsets):
//   part  @ 0       : 8 * 2048 * 256 = 4,194,304 (16 MB; gemm2 reuses 6 slices)
//   h1ext @ 4194304 : 2048 * 384    =   786,432 (3 MB)  row-major [g][384]
//   aout  @ 4980736 : 4*256*128     =   131,072
//   cout  @ 5111808 : 4*256*128     =   131,072
// Attention branch of the reference is dead code (attn_out unused) — skipped.
//
// GEMM lane mapping (the round-4 fix): wave owns a 4-row quad (ONE uniform
// ds_read_b128 per k-step), lane owns 4 output cols (float4 W load, 1KB/wave
// coalesced). LDS pipe cost: 1 b128 per 16 FMAs (was 4 per 16).
// ===========================================================================

// GEMM1 partial: part[ksi][g][c] = sum_{k in 128-slice} x[g][k] * wa1[k][c]
// grid 1024 = 128 row-tiles(16 rows) x 8 k-slices.
__global__ __launch_bounds__(256) void k_gemm1(
    const float* __restrict__ tracks, const float* __restrict__ dets,
    const float* __restrict__ wa1, float* __restrict__ part)
{
    __shared__ float xs[128 * 16];     // [f][r], r = row within tile
    const int blk = blockIdx.x;
    const int rt  = blk >> 3;
    const int ksi = blk & 7;
    const int g0  = rt * 16;
    const int side = g0 >> 10, b = (g0 >> 8) & 3, n0 = g0 & 255;
    const float* xb = (side ? dets : tracks) + (size_t)b * (1028 * 256);
    const int k0 = ksi * 128;
    const int tid = threadIdx.x;
    const int w   = tid >> 6;          // wave -> row quad (rows w*4..w*4+3)
    const int c0  = (tid & 63) * 4;    // lane -> 4 output cols

    // stage: lanes over r (16 floats/row), 4 f-rows per wave -> 4x64B segs
    for (int idx = tid; idx < 2048; idx += 256) {
        int f = idx >> 4, r = idx & 15;
        xs[f * 16 + r] = xb[(size_t)(k0 + f) * 256 + n0 + r];
    }
    __syncthreads();

    float acc[4][4];
#pragma unroll
    for (int i = 0; i < 4; ++i)
#pragma unroll
        for (int j = 0; j < 4; ++j) acc[i][j] = 0.f;

#pragma unroll 2
    for (int f = 0; f < 128; ++f) {
        float4 xv = *(const float4*)(xs + f * 16 + w * 4);           // uniform b128
        float4 wv = *(const float4*)(wa1 + (size_t)(k0 + f) * 256 + c0); // 1KB/wave
        acc[0][0] = fmaf(xv.x, wv.x, acc[0][0]);
        acc[0][1] = fmaf(xv.x, wv.y, acc[0][1]);
        acc[0][2] = fmaf(xv.x, wv.z, acc[0][2]);
        acc[0][3] = fmaf(xv.x, wv.w, acc[0][3]);
        acc[1][0] = fmaf(xv.y, wv.x, acc[1][0]);
        acc[1][1] = fmaf(xv.y, wv.y, acc[1][1]);
        acc[1][2] = fmaf(xv.y, wv.z, acc[1][2]);
        acc[1][3] = fmaf(xv.y, wv.w, acc[1][3]);
        acc[2][0] = fmaf(xv.z, wv.x, acc[2][0]);
        acc[2][1] = fmaf(xv.z, wv.y, acc[2][1]);
        acc[2][2] = fmaf(xv.z, wv.z, acc[2][2]);
        acc[2][3] = fmaf(xv.z, wv.w, acc[2][3]);
        acc[3][0] = fmaf(xv.w, wv.x, acc[3][0]);
        acc[3][1] = fmaf(xv.w, wv.y, acc[3][1]);
        acc[3][2] = fmaf(xv.w, wv.z, acc[3][2]);
        acc[3][3] = fmaf(xv.w, wv.w, acc[3][3]);
    }
    float* pb = part + ((size_t)ksi * 2048 + g0 + w * 4) * 256 + c0;
#pragma unroll
    for (int i = 0; i < 4; ++i)
        *(float4*)(pb + (size_t)i * 256) =
            make_float4(acc[i][0], acc[i][1], acc[i][2], acc[i][3]);
}

// Reduce 8 partials + ba1, LN(256), relu -> h1ext[g][0..255];
// geo MLP + LN(128) + relu -> h1ext[g][256..383].  grid 512 x 4 rows.
__global__ __launch_bounds__(256) void k_reduce1(
    const float* __restrict__ tracks, const float* __restrict__ dets,
    const float* __restrict__ part,
    const float* __restrict__ ba1, const float* __restrict__ gla,
    const float* __restrict__ bla,
    const float* __restrict__ wg1, const float* __restrict__ bg1,
    const float* __restrict__ glg, const float* __restrict__ blg,
    float* __restrict__ h1ext)
{
    __shared__ float red[4][4][2];
    __shared__ float geo_s[4][4];
    const int blk = blockIdx.x;
    const int g0 = blk * 4;
    const int side = g0 >> 10, b = (g0 >> 8) & 3, n0 = g0 & 255;
    const float* xb = (side ? dets : tracks) + (size_t)b * (1028 * 256);
    const int tid = threadIdx.x, wave = tid >> 6, lane = tid & 63, c = tid;

    if (tid < 16)
        geo_s[tid >> 2][tid & 3] =
            xb[(size_t)(1024 + (tid & 3)) * 256 + n0 + (tid >> 2)];

    float h[4];
#pragma unroll
    for (int i = 0; i < 4; ++i) {
        float s = ba1[c];
#pragma unroll
        for (int s8 = 0; s8 < 8; ++s8)
            s += part[((size_t)s8 * 2048 + g0 + i) * 256 + c];
        h[i] = s;
    }
#pragma unroll
    for (int i = 0; i < 4; ++i) {
        float s = h[i], s2 = h[i] * h[i];
#pragma unroll
        for (int off = 32; off >= 1; off >>= 1) {
            s  += __shfl_xor(s,  off, 64);
            s2 += __shfl_xor(s2, off, 64);
        }
        if (lane == 0) { red[wave][i][0] = s; red[wave][i][1] = s2; }
    }
    __syncthreads();
    {
        float gv = gla[c], bv = bla[c];
#pragma unroll
        for (int i = 0; i < 4; ++i) {
            float s  = red[0][i][0] + red[1][i][0] + red[2][i][0] + red[3][i][0];
            float s2 = red[0][i][1] + red[1][i][1] + red[2][i][1] + red[3][i][1];
            float m   = s * (1.f / 256.f);
            float var = s2 * (1.f / 256.f) - m * m;
            h1ext[(size_t)(g0 + i) * 384 + c] =
                fmaxf((h[i] - m) * rsqrtf(var + EPS) * gv + bv, 0.f);
        }
    }
    __syncthreads();   // red reads done before geo phase overwrites

    float gh[4];
    if (tid < 128) {
        const int j = tid;
#pragma unroll
        for (int i = 0; i < 4; ++i) {
            float s = bg1[j];
#pragma unroll
            for (int f = 0; f < 4; ++f)
                s = fmaf(geo_s[i][f], wg1[f * 128 + j], s);
            gh[i] = s;
        }
#pragma unroll
        for (int i = 0; i < 4; ++i) {
            float s = gh[i], s2 = gh[i] * gh[i];
#pragma unroll
            for (int off = 32; off >= 1; off >>= 1) {
                s  += __shfl_xor(s,  off, 64);
                s2 += __shfl_xor(s2, off, 64);
            }
            if (lane == 0) { red[wave][i][0] = s; red[wave][i][1] = s2; }
        }
    }
    __syncthreads();
    if (tid < 128) {
        const int j = tid;
        float gv = glg[j], bv = blg[j];
#pragma unroll
        for (int i = 0; i < 4; ++i) {
            float s  = red[0][i][0] + red[1][i][0];
            float s2 = red[0][i][1] + red[1][i][1];
            float m   = s * (1.f / 128.f);
            float var = s2 * (1.f / 128.f) - m * m;
            h1ext[(size_t)(g0 + i) * 384 + 256 + j] =
                fmaxf((gh[i] - m) * rsqrtf(var + EPS) * gv + bv, 0.f);
        }
    }
}

// GEMM2 partial: part[sl][g][c] = sum_{k in 64-slice} h1ext[g][k] * W[k][c]
// K=384 total, 6 slices of 64. grid 768 = 128 row-tiles x 6 slices.
__global__ __launch_bounds__(256) void k_gemm2(
    const float* __restrict__ h1ext,
    const float* __restrict__ wa2, const float* __restrict__ wg2,
    float* __restrict__ part)
{
    __shared__ float xs[64 * 16];
    const int blk = blockIdx.x;
    const int rt = blk / 6, sl = blk - rt * 6;
    const int g0 = rt * 16;
    const int k0 = sl * 64;
    const int tid = threadIdx.x;
    const int w   = tid >> 6;
    const int c0  = (tid & 63) * 4;
    const float* Wb = (k0 < 256) ? (wa2 + (size_t)k0 * 256)
                                 : (wg2 + (size_t)(k0 - 256) * 256);

    for (int idx = tid; idx < 1024; idx += 256) {
        int f = idx >> 4, r = idx & 15;
        xs[f * 16 + r] = h1ext[(size_t)(g0 + r) * 384 + k0 + f];
    }
    __syncthreads();

    float acc[4][4];
#pragma unroll
    for (int i = 0; i < 4; ++i)
#pragma unroll
        for (int j = 0; j < 4; ++j) acc[i][j] = 0.f;

#pragma unroll 2
    for (int f = 0; f < 64; ++f) {
        float4 xv = *(const float4*)(xs + f * 16 + w * 4);   // uniform b128
        float4 wv = *(const float4*)(Wb + (size_t)f * 256 + c0);
        acc[0][0] = fmaf(xv.x, wv.x, acc[0][0]);
        acc[0][1] = fmaf(xv.x, wv.y, acc[0][1]);
        acc[0][2] = fmaf(xv.x, wv.z, acc[0][2]);
        acc[0][3] = fmaf(xv.x, wv.w, acc[0][3]);
        acc[1][0] = fmaf(xv.y, wv.x, acc[1][0]);
        acc[1][1] = fmaf(xv.y, wv.y, acc[1][1]);
        acc[1][2] = fmaf(xv.y, wv.z, acc[1][2]);
        acc[1][3] = fmaf(xv.y, wv.w, acc[1][3]);
        acc[2][0] = fmaf(xv.z, wv.x, acc[2][0]);
        acc[2][1] = fmaf(xv.z, wv.y, acc[2][1]);
        acc[2][2] = fmaf(xv.z, wv.z, acc[2][2]);
        acc[2][3] = fmaf(xv.z, wv.w, acc[2][3]);
        acc[3][0] = fmaf(xv.w, wv.x, acc[3][0]);
        acc[3][1] = fmaf(xv.w, wv.y, acc[3][1]);
        acc[3][2] = fmaf(xv.w, wv.z, acc[3][2]);
        acc[3][3] = fmaf(xv.w, wv.w, acc[3][3]);
    }
    float* pb = part + ((size_t)sl * 2048 + g0 + w * 4) * 256 + c0;
#pragma unroll
    for (int i = 0; i < 4; ++i)
        *(float4*)(pb + (size_t)i * 256) =
            make_float4(acc[i][0], acc[i][1], acc[i][2], acc[i][3]);
}

// Reduce 6 partials + ba2+bg2, LN(gf,bf), project with wc1 half -> a/c rows.
// grid 512 x 4 rows.
__global__ __launch_bounds__(256) void k_reduce2(
    const float* __restrict__ part,
    const float* __restrict__ ba2, const float* __restrict__ bg2,
    const float* __restrict__ gf,  const float* __restrict__ bf,
    const float* __restrict__ wc1,
    float* __restrict__ aout, float* __restrict__ cout)
{
    __shared__ float red[4][4][2];
    __shared__ float emb[256 * 4];        // [k][row]
    __shared__ float psum[2][4][128];
    const int blk = blockIdx.x;
    const int g0 = blk * 4;
    const int side = g0 >> 10, b = (g0 >> 8) & 3, nin = g0 & 255;
    const int tid = threadIdx.x, wave = tid >> 6, lane = tid & 63, c = tid;

    float h2[4];
#pragma unroll
    for (int i = 0; i < 4; ++i) {
        float s = ba2[c] + bg2[c];
#pragma unroll
        for (int sl = 0; sl < 6; ++sl)
            s += part[((size_t)sl * 2048 + g0 + i) * 256 + c];
        h2[i] = s;
    }
#pragma unroll
    for (int i = 0; i < 4; ++i) {
        float s = h2[i], s2 = h2[i] * h2[i];
#pragma unroll
        for (int off = 32; off >= 1; off >>= 1) {
            s  += __shfl_xor(s,  off, 64);
            s2 += __shfl_xor(s2, off, 64);
        }
        if (lane == 0) { red[wave][i][0] = s; red[wave][i][1] = s2; }
    }
    __syncthreads();
    {
        float gv = gf[c], bv = bf[c];
        float e[4];
#pragma unroll
        for (int i = 0; i < 4; ++i) {
            float s  = red[0][i][0] + red[1][i][0] + red[2][i][0] + red[3][i][0];
            float s2 = red[0][i][1] + red[1][i][1] + red[2][i][1] + red[3][i][1];
            float m   = s * (1.f / 256.f);
            float var = s2 * (1.f / 256.f) - m * m;
            e[i] = (h2[i] - m) * rsqrtf(var + EPS) * gv + bv;
        }
        *(float4*)(emb + (size_t)c * 4) = make_float4(e[0], e[1], e[2], e[3]);
    }
    __syncthreads();

    const int half = tid >> 7, j = tid & 127;
    const float* wch = wc1 + (size_t)side * (256 * 128);
    float a4[4] = {0.f, 0.f, 0.f, 0.f};
#pragma unroll 4
    for (int k = 0; k < 128; ++k) {
        int kk = half * 128 + k;
        float w = wch[(size_t)kk * 128 + j];                  // coalesced
        float4 ev = *(const float4*)(emb + kk * 4);           // broadcast
        a4[0] = fmaf(ev.x, w, a4[0]); a4[1] = fmaf(ev.y, w, a4[1]);
        a4[2] = fmaf(ev.z, w, a4[2]); a4[3] = fmaf(ev.w, w, a4[3]);
    }
#pragma unroll
    for (int i = 0; i < 4; ++i) psum[half][i][j] = a4[i];
    __syncthreads();

    float* outp = (side ? cout : aout) + ((size_t)b * 256 + nin) * 128;
    for (int idx = tid; idx < 512; idx += 256) {
        int i = idx >> 7, jo = idx & 127;
        outp[(size_t)i * 128 + jo] = psum[0][i][jo] + psum[1][i][jo];
    }
}

// Pairwise: logits[b,n,m] = sum_j relu(a[n,j]+c[m,j]+bc1[j])*wc2[j] + bc2
// 32x32 tile/block, 2x2 outputs/thread, grid 256.
__global__ __launch_bounds__(256) void k_pairwise(
    const float* __restrict__ a, const float* __restrict__ cmat,
    const float* __restrict__ bc1, const float* __restrict__ wc2,
    const float* __restrict__ bc2, float* __restrict__ out)
{
    __shared__ float4 a_s[32 * 33];
    __shared__ float4 c_s[32 * 33];
    const int blk = blockIdx.x;               // 4 * 8 * 8 = 256
    const int b  = blk >> 6;
    const int n0 = ((blk >> 3) & 7) << 5;
    const int m0 = (blk & 7) << 5;
    const int tid = threadIdx.x;

    const float4* a4  = (const float4*)(a    + ((size_t)b * 256 + n0) * 128);
    const float4* c4  = (const float4*)(cmat + ((size_t)b * 256 + m0) * 128);
    const float4* b14 = (const float4*)bc1;
    for (int idx = tid; idx < 1024; idx += 256) {
        int r = idx >> 5, q = idx & 31;
        float4 av = a4[r * 32 + q], bv = b14[q];
        a_s[r * 33 + q] = make_float4(av.x + bv.x, av.y + bv.y,
                                      av.z + bv.z, av.w + bv.w);
        c_s[r * 33 + q] = c4[r * 32 + q];
    }
    __syncthreads();

    const int ni = tid >> 4, mi = tid & 15;
    const float4* wp = (const float4*)wc2;
    float s00 = 0.f, s01 = 0.f, s10 = 0.f, s11 = 0.f;
#pragma unroll 4
    for (int q = 0; q < 32; ++q) {
        float4 av0 = a_s[ni * 33 + q];
        float4 av1 = a_s[(ni + 16) * 33 + q];
        float4 cv0 = c_s[mi * 33 + q];
        float4 cv1 = c_s[(mi + 16) * 33 + q];
        float4 wv  = wp[q];                                   // uniform s_load
        s00 = fmaf(fmaxf(av0.x + cv0.x, 0.f), wv.x, s00);
        s00 = fmaf(fmaxf(av0.y + cv0.y, 0.f), wv.y, s00);
        s00 = fmaf(fmaxf(av0.z + cv0.z, 0.f), wv.z, s00);
        s00 = fmaf(fmaxf(av0.w + cv0.w, 0.f), wv.w, s00);
        s01 = fmaf(fmaxf(av0.x + cv1.x, 0.f), wv.x, s01);
        s01 = fmaf(fmaxf(av0.y + cv1.y, 0.f), wv.y, s01);
        s01 = fmaf(fmaxf(av0.z + cv1.z, 0.f), wv.z, s01);
        s01 = fmaf(fmaxf(av0.w + cv1.w, 0.f), wv.w, s01);
        s10 = fmaf(fmaxf(av1.x + cv0.x, 0.f), wv.x, s10);
        s10 = fmaf(fmaxf(av1.y + cv0.y, 0.f), wv.y, s10);
        s10 = fmaf(fmaxf(av1.z + cv0.z, 0.f), wv.z, s10);
        s10 = fmaf(fmaxf(av1.w + cv0.w, 0.f), wv.w, s10);
        s11 = fmaf(fmaxf(av1.x + cv1.x, 0.f), wv.x, s11);
        s11 = fmaf(fmaxf(av1.y + cv1.y, 0.f), wv.y, s11);
        s11 = fmaf(fmaxf(av1.z + cv1.z, 0.f), wv.z, s11);
        s11 = fmaf(fmaxf(av1.w + cv1.w, 0.f), wv.w, s11);
    }
    const float b2 = bc2[0];
    float* ob = out + ((size_t)b * 256 + n0) * 256 + m0;
    ob[(size_t)ni * 256 + mi]               = s00 + b2;
    ob[(size_t)ni * 256 + mi + 16]          = s01 + b2;
    ob[(size_t)(ni + 16) * 256 + mi]        = s10 + b2;
    ob[(size_t)(ni + 16) * 256 + mi + 16]   = s11 + b2;
}

extern "C" void kernel_launch(void* const* d_in, const int* in_sizes, int n_in,
                              void* d_out, int out_size, void* d_ws, size_t ws_size,
                              hipStream_t stream)
{
    const float* tracks = (const float*)d_in[0];
    const float* dets   = (const float*)d_in[1];
    const float* wa1 = (const float*)d_in[2];
    const float* ba1 = (const float*)d_in[3];
    const float* gla = (const float*)d_in[4];
    const float* bla = (const float*)d_in[5];
    const float* wa2 = (const float*)d_in[6];
    const float* ba2 = (const float*)d_in[7];
    const float* wg1 = (const float*)d_in[8];
    const float* bg1 = (const float*)d_in[9];
    const float* glg = (const float*)d_in[10];
    const float* blg = (const float*)d_in[11];
    const float* wg2 = (const float*)d_in[12];
    const float* bg2 = (const float*)d_in[13];
    const float* gf  = (const float*)d_in[14];
    const float* bf  = (const float*)d_in[15];
    // d_in[16..23]: attention weights — dead code in reference.
    const float* wc1 = (const float*)d_in[24];
    const float* bc1 = (const float*)d_in[25];
    const float* wc2 = (const float*)d_in[26];
    const float* bc2 = (const float*)d_in[27];
    float* out = (float*)d_out;
    float* ws  = (float*)d_ws;

    float* part  = ws;
    float* h1ext = ws + 4194304;
    float* aa    = ws + 4980736;
    float* cc    = ws + 5111808;

    hipLaunchKernelGGL(k_gemm1, dim3(1024), dim3(256), 0, stream,
                       tracks, dets, wa1, part);
    hipLaunchKernelGGL(k_reduce1, dim3(512), dim3(256), 0, stream,
                       tracks, dets, part, ba1, gla, bla,
                       wg1, bg1, glg, blg, h1ext);
    hipLaunchKernelGGL(k_gemm2, dim3(768), dim3(256), 0, stream,
                       h1ext, wa2, wg2, part);
    hipLaunchKernelGGL(k_reduce2, dim3(512), dim3(256), 0, stream,
                       part, ba2, bg2, gf, bf, wc1, aa, cc);
    hipLaunchKernelGGL(k_pairwise, dim3(256), dim3(256), 0, stream,
                       aa, cc, bc1, wc2, bc2, out);
}